// Round 8
// baseline (955.832 us; speedup 1.0000x reference)
//
#include <hip/hip_runtime.h>
#include <hip/hip_fp16.h>
#include <hip/hip_cooperative_groups.h>

namespace cg = cooperative_groups;

#define DD 128            // emb dim, fixed by problem
#define SCAN_CHUNK 1024   // rows per scan chunk
#define G_ROWS 32         // rows per gather tile (8 lanes/row-half * 32 rows = 256)
#define G_STAGE 1024      // staged edges per gather tile (mean 512, +22 sigma)

typedef float          f32x4 __attribute__((ext_vector_type(4)));
typedef unsigned int   u32x4 __attribute__((ext_vector_type(4)));
typedef unsigned int   u32x2 __attribute__((ext_vector_type(2)));
typedef unsigned short u16x8 __attribute__((ext_vector_type(8)));

struct __align__(8) Edge { int c; float v; };

struct KArgs {
    const int* rows; const int* cols; const float* vals;
    const float* emb; const float* u1; const float* u2;
    ushort* g1; ushort* g2; ushort* p16; ushort* emb16;
    unsigned int* cnt16; int* rs; ushort* rank; int* bsum;
    unsigned char* mask2; Edge* ev; float* out;
    int N, E, total8, dom1, nScanBlocks, nTilesX, NW;
};

// ---- fp16 helpers ----
__device__ __forceinline__ unsigned short f2h(float f) {
    return __half_as_ushort(__float2half(f));
}
__device__ __forceinline__ float2 up2(unsigned int u) {
    __half2 h = *reinterpret_cast<const __half2*>(&u);
    return __half22float2(h);
}

// ---- non-temporal helpers (keep L2/L3 for the gather working set) ----
template <typename T>
__device__ __forceinline__ T ldnt(const T* p) { return __builtin_nontemporal_load(p); }
template <typename T>
__device__ __forceinline__ void stnt(T* p, T v) { __builtin_nontemporal_store(v, p); }

// ---- P1: packed-16b hist + ALL dense prep (emb read ONCE) ------------------
// i < total8: read emb/u1/u2 once -> g1 (dropout, fp16), emb16 (fp16),
// mask2 (u2 dropout bits). i < E: hist atomic + rank store; the atomic
// chain hides under the stream loads issued in the same iteration.
__device__ __forceinline__ void p1_body(const KArgs& a, int i) {
    bool doE = i < a.E;
    bool doS = i < a.total8;
    int r = 0;
    if (doE) r = ldnt(a.rows + i);          // chain head issues first
    f32x4 hA, hB, uA, uB, wA, wB;
    if (doS) {
        const f32x4* e4 = (const f32x4*)a.emb;
        const f32x4* a4 = (const f32x4*)a.u1;
        const f32x4* b4 = (const f32x4*)a.u2;
        hA = ldnt(e4 + 2 * (size_t)i);
        hB = ldnt(e4 + 2 * (size_t)i + 1);
        uA = ldnt(a4 + 2 * (size_t)i);
        uB = ldnt(a4 + 2 * (size_t)i + 1);
        wA = ldnt(b4 + 2 * (size_t)i);
        wB = ldnt(b4 + 2 * (size_t)i + 1);
    }
    if (doE) {
        int sh = (r & 1) << 4;
        unsigned int old = atomicAdd(&a.cnt16[r >> 1], 1u << sh);
        stnt(a.rank + i, (ushort)((old >> sh) & 0xFFFFu));
    }
    if (doS) {
        const float s = 1.0f / 0.9f;
        u16x8 g;
        g[0] = f2h((uA.x >= 0.1f) ? hA.x * s : 0.0f);
        g[1] = f2h((uA.y >= 0.1f) ? hA.y * s : 0.0f);
        g[2] = f2h((uA.z >= 0.1f) ? hA.z * s : 0.0f);
        g[3] = f2h((uA.w >= 0.1f) ? hA.w * s : 0.0f);
        g[4] = f2h((uB.x >= 0.1f) ? hB.x * s : 0.0f);
        g[5] = f2h((uB.y >= 0.1f) ? hB.y * s : 0.0f);
        g[6] = f2h((uB.z >= 0.1f) ? hB.z * s : 0.0f);
        g[7] = f2h((uB.w >= 0.1f) ? hB.w * s : 0.0f);
        ((u16x8*)a.g1)[i] = g;              // normal store: gather1 working set
        u16x8 e16;
        e16[0] = f2h(hA.x); e16[1] = f2h(hA.y); e16[2] = f2h(hA.z); e16[3] = f2h(hA.w);
        e16[4] = f2h(hB.x); e16[5] = f2h(hB.y); e16[6] = f2h(hB.z); e16[7] = f2h(hB.w);
        stnt((u16x8*)a.emb16 + i, e16);
        unsigned char m =
            (unsigned char)((wA.x >= 0.1f ? 1u : 0u)  | (wA.y >= 0.1f ? 2u : 0u)  |
                            (wA.z >= 0.1f ? 4u : 0u)  | (wA.w >= 0.1f ? 8u : 0u)  |
                            (wB.x >= 0.1f ? 16u : 0u) | (wB.y >= 0.1f ? 32u : 0u) |
                            (wB.z >= 0.1f ? 64u : 0u) | (wB.w >= 0.1f ? 128u : 0u));
        stnt(a.mask2 + i, m);
    }
}

// ---- P2a: per-chunk scan of packed counters -> rs (chunk-local) + bsum -----
__device__ __forceinline__ void d_scan_chunk(int b, const KArgs& a, int* s) {
    int tid = threadIdx.x;
    int n = a.N;
    int base = b * SCAN_CHUNK + tid * 4;    // even
    int c0 = 0, c1 = 0, c2 = 0, c3 = 0;
    if (base < n) {
        unsigned int w0 = a.cnt16[base >> 1];
        c0 = (int)(w0 & 0xFFFFu); c1 = (int)(w0 >> 16);
    }
    if (base + 2 < n) {
        unsigned int w1 = a.cnt16[(base >> 1) + 1];
        c2 = (int)(w1 & 0xFFFFu); c3 = (int)(w1 >> 16);
    }
    int tsum = c0 + c1 + c2 + c3;
    s[tid] = tsum;
    __syncthreads();
    for (int off = 1; off < 256; off <<= 1) {
        int t = (tid >= off) ? s[tid - off] : 0;
        __syncthreads();
        s[tid] += t;
        __syncthreads();
    }
    int excl = s[tid] - tsum;
    if (tid == 255) a.bsum[b] = s[255];
    if (base < n)     a.rs[base]     = excl;
    if (base + 1 < n) a.rs[base + 1] = excl + c0;
    if (base + 2 < n) a.rs[base + 2] = excl + c0 + c1;
    if (base + 3 < n) a.rs[base + 3] = excl + c0 + c1 + c2;
}

// ---- P3: pure edge scatter (stream moved to P1) ----------------------------
__device__ __forceinline__ void p3_body(const KArgs& a, int i) {
    int r = ldnt(a.rows + i);
    int c = ldnt(a.cols + i);
    float v = ldnt(a.vals + i);
    unsigned int rk = ldnt(a.rank + i);
    int pos = a.rs[r] + (int)rk;            // hot 400KB, L2
    u32x2 q;
    q.x = (unsigned int)c;
    q.y = __float_as_uint(v);
    ((u32x2*)a.ev)[pos] = q;
}

// ---- gather tile: 32 rows, 8 lanes/row-half, 16B loads, split-D ------------
// MODE 1: p16 = fp16(h1 = A*g1); g2 = fp16(dropout(h1) via mask2 bits)
// MODE 2: out = (emb16 + p16 + A*g2) / 3   [fp32]
template <int MODE>
__device__ __forceinline__ void gather_tile(const KArgs& a, int tileX, int h,
                                            int* s_rs, Edge* s_ev) {
    int tid = threadIdx.x;
    int r0 = tileX * G_ROWS;
    __syncthreads();                        // protect prev tile's LDS reads
    if (tid <= G_ROWS) {
        int r = r0 + tid;
        s_rs[tid] = (r < a.N) ? a.rs[r] : a.E;
    }
    __syncthreads();
    int base = s_rs[0];
    int nblk = s_rs[G_ROWS] - base;
    int nstage = nblk < G_STAGE ? nblk : G_STAGE;
    for (int i = tid; i < nstage; i += 256) {
        u32x2 q = ldnt((const u32x2*)(a.ev + base + i));
        Edge ed; ed.c = (int)q.x; ed.v = __uint_as_float(q.y);
        s_ev[i] = ed;
    }
    __syncthreads();

    int grp = tid >> 3;
    int lane = tid & 7;
    int row = r0 + grp;
    if (row >= a.N) return;                 // no barriers below: safe skip
    int start = s_rs[grp] - base;
    int end = s_rs[grp + 1] - base;
    int eL = end < nstage ? end : nstage;

    const ushort* srch = (MODE == 1) ? a.g1 : a.g2;
    const u32x4* s4 = (const u32x4*)srch;   // 16 u32x4 per row
    const Edge* evg = a.ev + base;
    int hoff = (h << 3) + lane;             // u32x4 index within row
    float a0 = 0.f, a1 = 0.f, a2 = 0.f, a3 = 0.f;
    float a4 = 0.f, a5 = 0.f, a6 = 0.f, a7 = 0.f;

#define LDE(i) Edge E##i = s_ev[e + i]; float fv##i = E##i.v;
#define LDP(i) int ix##i = e + i; bool ok##i = ix##i < eL; \
               Edge E##i = s_ev[ok##i ? ix##i : last]; \
               float fv##i = ok##i ? E##i.v : 0.0f;
#define GQ(i)  u32x4 q##i = s4[((size_t)E##i.c << 4) + hoff];
#define ACC(i) { float vv = fv##i; \
        float2 w0 = up2(q##i.x), w1 = up2(q##i.y), w2 = up2(q##i.z), w3 = up2(q##i.w); \
        a0 = fmaf(vv, w0.x, a0); a1 = fmaf(vv, w0.y, a1); \
        a2 = fmaf(vv, w1.x, a2); a3 = fmaf(vv, w1.y, a3); \
        a4 = fmaf(vv, w2.x, a4); a5 = fmaf(vv, w2.y, a5); \
        a6 = fmaf(vv, w3.x, a6); a7 = fmaf(vv, w3.y, a7); }

    int e = start;
    for (; e + 8 <= eL; e += 8) {
        LDE(0) LDE(1) LDE(2) LDE(3) LDE(4) LDE(5) LDE(6) LDE(7)
        GQ(0) GQ(1) GQ(2) GQ(3) GQ(4) GQ(5) GQ(6) GQ(7)
        ACC(0) ACC(1) ACC(2) ACC(3) ACC(4) ACC(5) ACC(6) ACC(7)
    }
    if (e < eL) {   // predicated 8-batch: remainder 1..7 in ONE latency round
        int last = eL - 1;
        LDP(0) LDP(1) LDP(2) LDP(3) LDP(4) LDP(5) LDP(6) LDP(7)
        GQ(0) GQ(1) GQ(2) GQ(3) GQ(4) GQ(5) GQ(6) GQ(7)
        ACC(0) ACC(1) ACC(2) ACC(3) ACC(4) ACC(5) ACC(6) ACC(7)
        e = eL;
    }
    for (; e < end; ++e) {  // rare spill past G_STAGE: finish from global
        Edge E0; { u32x2 q_ = ldnt((const u32x2*)(evg + e));
                   E0.c = (int)q_.x; E0.v = __uint_as_float(q_.y); }
        float fv0 = E0.v;
        GQ(0) ACC(0)
    }
#undef LDE
#undef LDP
#undef GQ
#undef ACC

    size_t o = ((size_t)row << 7) + ((size_t)h << 6) + (size_t)lane * 8;
    if (MODE == 1) {
        unsigned int m = a.mask2[(size_t)row * 16 + (h << 3) + lane];
        const float s = 1.0f / 0.9f;
        u16x8 gg;
        gg[0] = (m & 1u)   ? f2h(a0 * s) : (ushort)0;
        gg[1] = (m & 2u)   ? f2h(a1 * s) : (ushort)0;
        gg[2] = (m & 4u)   ? f2h(a2 * s) : (ushort)0;
        gg[3] = (m & 8u)   ? f2h(a3 * s) : (ushort)0;
        gg[4] = (m & 16u)  ? f2h(a4 * s) : (ushort)0;
        gg[5] = (m & 32u)  ? f2h(a5 * s) : (ushort)0;
        gg[6] = (m & 64u)  ? f2h(a6 * s) : (ushort)0;
        gg[7] = (m & 128u) ? f2h(a7 * s) : (ushort)0;
        stnt((u16x8*)(a.g2 + o), gg);
        u16x8 pp;
        pp[0] = f2h(a0); pp[1] = f2h(a1); pp[2] = f2h(a2); pp[3] = f2h(a3);
        pp[4] = f2h(a4); pp[5] = f2h(a5); pp[6] = f2h(a6); pp[7] = f2h(a7);
        stnt((u16x8*)(a.p16 + o), pp);
    } else {
        u32x4 eq = ldnt((const u32x4*)(a.emb16 + o));
        u32x4 pq = ldnt((const u32x4*)(a.p16 + o));
        float2 e0 = up2(eq.x), e1 = up2(eq.y), e2 = up2(eq.z), e3 = up2(eq.w);
        float2 p0 = up2(pq.x), p1 = up2(pq.y), p2 = up2(pq.z), p3 = up2(pq.w);
        const float t3 = 1.0f / 3.0f;
        f32x4 rA, rB;
        rA.x = (e0.x + p0.x + a0) * t3;
        rA.y = (e0.y + p0.y + a1) * t3;
        rA.z = (e1.x + p1.x + a2) * t3;
        rA.w = (e1.y + p1.y + a3) * t3;
        rB.x = (e2.x + p2.x + a4) * t3;
        rB.y = (e2.y + p2.y + a5) * t3;
        rB.z = (e3.x + p3.x + a6) * t3;
        rB.w = (e3.y + p3.y + a7) * t3;
        stnt((f32x4*)(a.out + o), rA);
        stnt((f32x4*)(a.out + o) + 1, rB);
    }
}

// ---- THE mega-kernel: one cooperative dispatch, grid.sync between phases ---
// Eliminates ~6 inter-dispatch gaps (~100us measured as sum-of-kernels vs
// total). __launch_bounds__(256,6): 6 blocks/CU co-resident, VGPR<=85.
__global__ __launch_bounds__(256, 6) void k_mega(KArgs a) {
    cg::grid_group grid = cg::this_grid();
    __shared__ int s_rs[G_ROWS + 1];
    __shared__ Edge s_ev[G_STAGE];      // 8KB
    __shared__ int s_scan[256];
    __shared__ int s_pref[1024];

    const int NT = (int)gridDim.x * 256;
    const int tid = threadIdx.x;
    const int gid = (int)blockIdx.x * 256 + tid;

    // P0: zero packed counters
    for (int i = gid; i < a.NW; i += NT) a.cnt16[i] = 0u;
    grid.sync();

    // P1: hist + g1/emb16/mask2 prep (emb read once)
    for (int i = gid; i < a.dom1; i += NT) p1_body(a, i);
    grid.sync();

    // P2a: chunk scans (first nScanBlocks blocks)
    if ((int)blockIdx.x < a.nScanBlocks) d_scan_chunk((int)blockIdx.x, a, s_scan);
    grid.sync();

    // P2b: redundant per-block bsum prefix + add chunk offsets -> rs absolute
    for (int i = tid; i < a.nScanBlocks; i += 256) s_pref[i] = a.bsum[i];
    __syncthreads();
    if (tid == 0) {
        int run = 0;
        for (int i = 0; i < a.nScanBlocks; ++i) { int t = s_pref[i]; s_pref[i] = run; run += t; }
    }
    __syncthreads();
    for (int i = gid; i < a.N; i += NT) a.rs[i] += s_pref[i >> 10];
    grid.sync();

    // P3: pure edge scatter
    for (int i = gid; i < a.E; i += NT) p3_body(a, i);
    grid.sync();

    // P4: gather layer 1 (h=0 tiles first, then h=1: halved working set)
    int nT2 = a.nTilesX * 2;
    for (int t = (int)blockIdx.x; t < nT2; t += (int)gridDim.x) {
        int h = (t >= a.nTilesX) ? 1 : 0;
        int tx = h ? (t - a.nTilesX) : t;
        gather_tile<1>(a, tx, h, s_rs, s_ev);
    }
    grid.sync();

    // P5: gather layer 2
    for (int t = (int)blockIdx.x; t < nT2; t += (int)gridDim.x) {
        int h = (t >= a.nTilesX) ? 1 : 0;
        int tx = h ? (t - a.nTilesX) : t;
        gather_tile<2>(a, tx, h, s_rs, s_ev);
    }
}

// ---- fallback kernels (classic pipeline, same phase bodies) ----------------
__global__ __launch_bounds__(256) void k_f_p1(KArgs a) {
    int gid = blockIdx.x * 256 + threadIdx.x;
    int NT = gridDim.x * 256;
    for (int i = gid; i < a.dom1; i += NT) p1_body(a, i);
}
__global__ __launch_bounds__(256) void k_f_scan1(KArgs a) {
    __shared__ int s[256];
    d_scan_chunk((int)blockIdx.x, a, s);
}
__global__ __launch_bounds__(256) void k_f_p2b(KArgs a) {
    __shared__ int s_pref[1024];
    int tid = threadIdx.x;
    for (int i = tid; i < a.nScanBlocks; i += 256) s_pref[i] = a.bsum[i];
    __syncthreads();
    if (tid == 0) {
        int run = 0;
        for (int i = 0; i < a.nScanBlocks; ++i) { int t = s_pref[i]; s_pref[i] = run; run += t; }
    }
    __syncthreads();
    int i = blockIdx.x * 256 + tid;
    if (i < a.N) a.rs[i] += s_pref[i >> 10];
}
__global__ __launch_bounds__(256) void k_f_p3(KArgs a) {
    int gid = blockIdx.x * 256 + threadIdx.x;
    int NT = gridDim.x * 256;
    for (int i = gid; i < a.E; i += NT) p3_body(a, i);
}
template <int MODE>
__global__ __launch_bounds__(256) void k_f_g(KArgs a) {
    __shared__ int s_rs[G_ROWS + 1];
    __shared__ Edge s_ev[G_STAGE];
    gather_tile<MODE>(a, (int)blockIdx.x, (int)blockIdx.y, s_rs, s_ev);
}

// ---- launch -------------------------------------------------------------

extern "C" void kernel_launch(void* const* d_in, const int* in_sizes, int n_in,
                              void* d_out, int out_size, void* d_ws, size_t ws_size,
                              hipStream_t stream) {
    const int* rows = (const int*)d_in[1];
    const int* cols = (const int*)d_in[2];
    const float* vals = (const float*)d_in[3];
    const float* emb = (const float*)d_in[4];
    const float* u1 = (const float*)d_in[5];
    const float* u2 = (const float*)d_in[6];
    float* out = (float*)d_out;

    const int N = in_sizes[0];
    const int E = in_sizes[1];
    const size_t ND = (size_t)N * DD;
    const int NW = (N + 1) / 2;

    // workspace layout (~121 MB)
    char* ws = (char*)d_ws;
    Edge* ev     = (Edge*)ws;   ws += (size_t)E * sizeof(Edge);        // 12.8MB
    ushort* g1   = (ushort*)ws; ws += ND * sizeof(ushort);             // 25.6MB fp16
    ushort* g2   = (ushort*)ws; ws += ND * sizeof(ushort);             // 25.6MB fp16
    ushort* p16  = (ushort*)ws; ws += ND * sizeof(ushort);             // 25.6MB fp16 h1
    ushort* emb16= (ushort*)ws; ws += ND * sizeof(ushort);             // 25.6MB fp16 emb
    unsigned int* cnt16 = (unsigned int*)ws; ws += (size_t)NW * 4;     // 200KB packed
    int* rs      = (int*)ws;    ws += (size_t)N * sizeof(int);         // 0.4MB rowstart
    ushort* rank = (ushort*)ws; ws += (size_t)E * sizeof(ushort);      // 3.2MB
    int* bsum    = (int*)ws;    ws += 4096;
    unsigned char* mask2 = (unsigned char*)ws;                         // 1.6MB

    const int total8 = (int)(ND / 8);
    const int dom1 = total8 > E ? total8 : E;
    const int nScanBlocks = (N + SCAN_CHUNK - 1) / SCAN_CHUNK;
    const int nTilesX = (N + G_ROWS - 1) / G_ROWS;

    KArgs ka;
    ka.rows = rows; ka.cols = cols; ka.vals = vals;
    ka.emb = emb; ka.u1 = u1; ka.u2 = u2;
    ka.g1 = g1; ka.g2 = g2; ka.p16 = p16; ka.emb16 = emb16;
    ka.cnt16 = cnt16; ka.rs = rs; ka.rank = rank; ka.bsum = bsum;
    ka.mask2 = mask2; ka.ev = ev; ka.out = out;
    ka.N = N; ka.E = E; ka.total8 = total8; ka.dom1 = dom1;
    ka.nScanBlocks = nScanBlocks; ka.nTilesX = nTilesX; ka.NW = NW;

    // co-resident grid size (cached); coop launch validates residency
    static int NB = 0;
    static bool coopOK = true;
    if (NB == 0) {
        int dev = 0;
        hipGetDevice(&dev);
        hipDeviceProp_t prop{};
        hipGetDeviceProperties(&prop, dev);
        int nbcu = 0;
        hipError_t oe = hipOccupancyMaxActiveBlocksPerMultiprocessor(&nbcu, k_mega, 256, 0);
        if (oe != hipSuccess || nbcu < 1 || !prop.cooperativeLaunch) coopOK = false;
        int ncu = prop.multiProcessorCount > 0 ? prop.multiProcessorCount : 256;
        NB = (nbcu < 1 ? 1 : nbcu) * ncu;
        if (NB < 256) NB = 256;
        if (NB > 8192) NB = 8192;
    }

    bool launched = false;
    if (coopOK) {
        void* params[] = { (void*)&ka };
        hipError_t err = hipLaunchCooperativeKernel((const void*)k_mega, dim3(NB),
                                                    dim3(256), params, 0, stream);
        if (err == hipSuccess) {
            launched = true;
        } else {
            coopOK = false;
            (void)hipGetLastError();   // clear sticky error before fallback
        }
    }
    if (!launched) {
        // classic pipeline (same bodies, kernel boundaries as fences)
        hipMemsetAsync(cnt16, 0, (size_t)NW * 4, stream);
        k_f_p1<<<(dom1 + 255) / 256, 256, 0, stream>>>(ka);
        k_f_scan1<<<nScanBlocks, 256, 0, stream>>>(ka);
        k_f_p2b<<<(N + 255) / 256, 256, 0, stream>>>(ka);
        k_f_p3<<<(E + 255) / 256, 256, 0, stream>>>(ka);
        k_f_g<1><<<dim3(nTilesX, 2), 256, 0, stream>>>(ka);
        k_f_g<2><<<dim3(nTilesX, 2), 256, 0, stream>>>(ka);
    }
}

// Round 9
// 404.331 us; speedup vs baseline: 2.3640x; 2.3640x over previous
//
#include <hip/hip_runtime.h>
#include <hip/hip_fp16.h>

#define DD 128            // emb dim, fixed by problem
#define SCAN_CHUNK 1024   // rows per scan1 block
#define G_ROWS 32         // rows per gather block (8 lanes/row-half * 32 rows = 256)
#define G_STAGE 1024      // staged edges per gather block (mean 512, +22 sigma)

typedef float          f32x4 __attribute__((ext_vector_type(4)));
typedef unsigned int   u32x4 __attribute__((ext_vector_type(4)));
typedef unsigned int   u32x2 __attribute__((ext_vector_type(2)));
typedef unsigned short u16x8 __attribute__((ext_vector_type(8)));

struct __align__(8) Edge { int c; float v; };

// ---- fp16 helpers ----
__device__ __forceinline__ unsigned short f2h(float f) {
    return __half_as_ushort(__float2half(f));
}
__device__ __forceinline__ float2 up2(unsigned int u) {
    __half2 h = *reinterpret_cast<const __half2*>(&u);
    return __half22float2(h);
}

// ---- non-temporal access helpers (keep L2/L3 for the gather working set) ----
template <typename T>
__device__ __forceinline__ T ldnt(const T* p) { return __builtin_nontemporal_load(p); }
template <typename T>
__device__ __forceinline__ void stnt(T* p, T v) { __builtin_nontemporal_store(v, p); }

// ---- K1: g1 = fp16(dropout(emb,u1)) stream + packed-16b hist ---------------
// Counters: 2 rows per 32-bit word (200KB). The 1.6M returning atomics are
// fabric-op-throughput-bound (~45us floor, verified rounds 3-7); they hide
// partially under the stream. Per-row count <= ~50 << 2^16: no carry.
__global__ __launch_bounds__(256) void k_g1hist(const float* __restrict__ emb,
                                                const float* __restrict__ u1,
                                                ushort* __restrict__ g1,
                                                const int* __restrict__ rows,
                                                unsigned int* __restrict__ cnt16,
                                                ushort* __restrict__ rank,
                                                int total8, int E) {
    int i = blockIdx.x * 256 + threadIdx.x;
    bool doE = i < E;
    bool doS = i < total8;
    int r = 0;
    if (doE) r = ldnt(rows + i);            // chain head issues first
    f32x4 hA, hB, uA, uB;
    if (doS) {                              // stream loads fly under the chain
        const f32x4* e4 = (const f32x4*)emb;
        const f32x4* a4 = (const f32x4*)u1;
        hA = ldnt(e4 + 2 * (size_t)i);
        hB = ldnt(e4 + 2 * (size_t)i + 1);
        uA = ldnt(a4 + 2 * (size_t)i);
        uB = ldnt(a4 + 2 * (size_t)i + 1);
    }
    if (doE) {
        int sh = (r & 1) << 4;
        unsigned int old = atomicAdd(&cnt16[r >> 1], 1u << sh);
        stnt(rank + i, (ushort)((old >> sh) & 0xFFFFu));
    }
    if (doS) {
        const float s = 1.0f / 0.9f;
        u16x8 g;
        g[0] = f2h((uA.x >= 0.1f) ? hA.x * s : 0.0f);
        g[1] = f2h((uA.y >= 0.1f) ? hA.y * s : 0.0f);
        g[2] = f2h((uA.z >= 0.1f) ? hA.z * s : 0.0f);
        g[3] = f2h((uA.w >= 0.1f) ? hA.w * s : 0.0f);
        g[4] = f2h((uB.x >= 0.1f) ? hB.x * s : 0.0f);
        g[5] = f2h((uB.y >= 0.1f) ? hB.y * s : 0.0f);
        g[6] = f2h((uB.z >= 0.1f) ? hB.z * s : 0.0f);
        g[7] = f2h((uB.w >= 0.1f) ? hB.w * s : 0.0f);
        ((u16x8*)g1)[i] = g;   // normal store: gather1's working set
    }
}

// scan1: read packed counters (200KB), per-thread 4 rows (2 words), block
// exclusive scan -> rs (chunk-local exclusive rowstart), block totals -> bsum.
__global__ __launch_bounds__(256) void k_scan1(const unsigned int* __restrict__ cnt16,
                                               int* __restrict__ rs,
                                               int* __restrict__ bsum, int n) {
    __shared__ int s[256];
    int tid = threadIdx.x;
    int base = blockIdx.x * SCAN_CHUNK + tid * 4;   // even
    int c0 = 0, c1 = 0, c2 = 0, c3 = 0;
    if (base < n) {                                  // n even: base+1 valid too
        unsigned int w0 = cnt16[base >> 1];
        c0 = (int)(w0 & 0xFFFFu);
        c1 = (int)(w0 >> 16);
    }
    if (base + 2 < n) {
        unsigned int w1 = cnt16[(base >> 1) + 1];
        c2 = (int)(w1 & 0xFFFFu);
        c3 = (int)(w1 >> 16);
    }
    int tsum = c0 + c1 + c2 + c3;
    s[tid] = tsum;
    __syncthreads();
    for (int off = 1; off < 256; off <<= 1) {
        int t = (tid >= off) ? s[tid - off] : 0;
        __syncthreads();
        s[tid] += t;
        __syncthreads();
    }
    int excl = s[tid] - tsum;
    if (tid == 255) bsum[blockIdx.x] = s[255];
    if (base < n)     rs[base]     = excl;
    if (base + 1 < n) rs[base + 1] = excl + c0;
    if (base + 2 < n) rs[base + 2] = excl + c0 + c1;
    if (base + 3 < n) rs[base + 3] = excl + c0 + c1 + c2;
}

// scan23: serial prefix of bsum (nb<=1024) in LDS, add chunk offset to rs.
// rs becomes the global rowstart.
__global__ __launch_bounds__(256) void k_scan23(int* __restrict__ rs,
                                                const int* __restrict__ bsum,
                                                int nb, int n) {
    __shared__ int s[1024];
    int tid = threadIdx.x;
    for (int i = tid; i < nb; i += 256) s[i] = bsum[i];
    __syncthreads();
    if (tid == 0) {
        int run = 0;
        for (int i = 0; i < nb; ++i) { int t = s[i]; s[i] = run; run += t; }
    }
    __syncthreads();
    int i = blockIdx.x * 256 + tid;
    if (i < n) rs[i] += s[i >> 10];
}

// ---- K4: 1-edge/thread scatter + emb16/mask2 stream ------------------------
// pos = rs[r] + rank[e] : ONE random (L2-hot, 400KB) load per edge, no
// atomic. Latency hides under the stream in the same wave.
__global__ __launch_bounds__(256) void k_scatter_prep(const int* __restrict__ rows,
                                                      const int* __restrict__ cols,
                                                      const float* __restrict__ vals,
                                                      const int* __restrict__ rs,
                                                      const ushort* __restrict__ rank,
                                                      Edge* __restrict__ ev,
                                                      const float* __restrict__ emb,
                                                      const float* __restrict__ u2,
                                                      ushort* __restrict__ emb16,
                                                      unsigned char* __restrict__ mask2,
                                                      int E, int total8) {
    int i = blockIdx.x * 256 + threadIdx.x;
    bool doE = i < E;
    bool doS = i < total8;
    int r = 0, c = 0; float vv = 0.f; unsigned int rk = 0;
    if (doE) {
        r = ldnt(rows + i);
        c = ldnt(cols + i);
        vv = ldnt(vals + i);
        rk = ldnt(rank + i);
    }
    f32x4 hA, hB, vA, vB;
    if (doS) {
        const f32x4* e4 = (const f32x4*)emb;
        const f32x4* b4 = (const f32x4*)u2;
        hA = ldnt(e4 + 2 * (size_t)i);
        hB = ldnt(e4 + 2 * (size_t)i + 1);
        vA = ldnt(b4 + 2 * (size_t)i);
        vB = ldnt(b4 + 2 * (size_t)i + 1);
    }
    if (doE) {
        int pos = rs[r] + (int)rk;    // hot 400KB, L2
        u32x2 q;
        q.x = (unsigned int)c;
        q.y = __float_as_uint(vv);
        ((u32x2*)ev)[pos] = q;        // normal store: L2/L3 absorbs amplification
    }
    if (doS) {
        u16x8 e16;
        e16[0] = f2h(hA.x); e16[1] = f2h(hA.y); e16[2] = f2h(hA.z); e16[3] = f2h(hA.w);
        e16[4] = f2h(hB.x); e16[5] = f2h(hB.y); e16[6] = f2h(hB.z); e16[7] = f2h(hB.w);
        stnt((u16x8*)emb16 + i, e16);
        unsigned char m =
            (unsigned char)((vA.x >= 0.1f ? 1u : 0u)  | (vA.y >= 0.1f ? 2u : 0u)  |
                            (vA.z >= 0.1f ? 4u : 0u)  | (vA.w >= 0.1f ? 8u : 0u)  |
                            (vB.x >= 0.1f ? 16u : 0u) | (vB.y >= 0.1f ? 32u : 0u) |
                            (vB.z >= 0.1f ? 64u : 0u) | (vB.w >= 0.1f ? 128u : 0u));
        stnt(mask2 + i, m);
    }
}

// ---- gather SpMM, split-D, 16-DEEP batches -------------------------------
// grid (N/32, 2): blockIdx.y picks the 64-wide D-half (halved working set).
// 32 rows/block, 8 lanes/row-half, 16B loads. Mean degree = 16, so one
// 16-deep batch covers most rows in ONE latency round (was 2-3 at 8-deep);
// remainder handled by ONE PREDICATED 16-batch (clamped index, zeroed
// multiplier -> exact no-op fmaf, summation order unchanged).
// __launch_bounds__(256,4): allow up to ~128 VGPR for the 16 in-flight loads.
// MODE 1: p16 = fp16(h1 = A*src); g2 = fp16(dropout(h1) via mask2 bits)
// MODE 2: out = (emb16 + p16in + A*src) / 3   [fp32]
template <int MODE>
__global__ __launch_bounds__(256, 4) void k_gather(const int* __restrict__ rowstart,
                                                   const Edge* __restrict__ ev,
                                                   const ushort* __restrict__ srch,
                                                   const unsigned char* __restrict__ mask2,
                                                   const ushort* __restrict__ emb16,
                                                   const ushort* __restrict__ p16in,
                                                   ushort* __restrict__ p16out,
                                                   ushort* __restrict__ g2,
                                                   float* __restrict__ out,
                                                   int N, int E) {
    __shared__ int s_rs[G_ROWS + 1];
    __shared__ Edge s_ev[G_STAGE];

    int tid = threadIdx.x;
    int r0 = blockIdx.x * G_ROWS;
    int h = blockIdx.y;                 // D-half: halves [h*64, h*64+64)
    if (tid <= G_ROWS) {
        int r = r0 + tid;
        s_rs[tid] = (r < N) ? rowstart[r] : E;
    }
    __syncthreads();
    int base = s_rs[0];
    int nblk = s_rs[G_ROWS] - base;
    int nstage = nblk < G_STAGE ? nblk : G_STAGE;
    for (int i = tid; i < nstage; i += 256) {
        u32x2 q = ldnt((const u32x2*)(ev + base + i));
        Edge ed; ed.c = (int)q.x; ed.v = __uint_as_float(q.y);
        s_ev[i] = ed;
    }
    __syncthreads();

    int grp = tid >> 3;
    int lane = tid & 7;
    int row = r0 + grp;
    if (row >= N) return;
    int start = s_rs[grp] - base;
    int end = s_rs[grp + 1] - base;
    int eL = end < nstage ? end : nstage;

    const u32x4* __restrict__ s4 = (const u32x4*)srch;  // 16 u32x4 per row
    const Edge* __restrict__ evg = ev + base;
    int hoff = (h << 3) + lane;                          // u32x4 index in row
    float a0 = 0.f, a1 = 0.f, a2 = 0.f, a3 = 0.f;
    float a4 = 0.f, a5 = 0.f, a6 = 0.f, a7 = 0.f;

#define LDE(i) Edge E##i = s_ev[e + i]; float fv##i = E##i.v;
#define LDP(i) int ix##i = e + i; bool ok##i = ix##i < eL; \
               Edge E##i = s_ev[ok##i ? ix##i : last]; \
               float fv##i = ok##i ? E##i.v : 0.0f;
#define GQ(i)  u32x4 q##i = s4[((size_t)E##i.c << 4) + hoff];
#define ACC(i) { float vv = fv##i; \
        float2 w0 = up2(q##i.x), w1 = up2(q##i.y), w2 = up2(q##i.z), w3 = up2(q##i.w); \
        a0 = fmaf(vv, w0.x, a0); a1 = fmaf(vv, w0.y, a1); \
        a2 = fmaf(vv, w1.x, a2); a3 = fmaf(vv, w1.y, a3); \
        a4 = fmaf(vv, w2.x, a4); a5 = fmaf(vv, w2.y, a5); \
        a6 = fmaf(vv, w3.x, a6); a7 = fmaf(vv, w3.y, a7); }

    int e = start;
    for (; e + 16 <= eL; e += 16) {
        LDE(0)  LDE(1)  LDE(2)  LDE(3)  LDE(4)  LDE(5)  LDE(6)  LDE(7)
        LDE(8)  LDE(9)  LDE(10) LDE(11) LDE(12) LDE(13) LDE(14) LDE(15)
        GQ(0)  GQ(1)  GQ(2)  GQ(3)  GQ(4)  GQ(5)  GQ(6)  GQ(7)
        GQ(8)  GQ(9)  GQ(10) GQ(11) GQ(12) GQ(13) GQ(14) GQ(15)
        ACC(0)  ACC(1)  ACC(2)  ACC(3)  ACC(4)  ACC(5)  ACC(6)  ACC(7)
        ACC(8)  ACC(9)  ACC(10) ACC(11) ACC(12) ACC(13) ACC(14) ACC(15)
    }
    if (e < eL) {   // predicated 16-batch: remainder 1..15 in ONE latency round
        int last = eL - 1;
        LDP(0)  LDP(1)  LDP(2)  LDP(3)  LDP(4)  LDP(5)  LDP(6)  LDP(7)
        LDP(8)  LDP(9)  LDP(10) LDP(11) LDP(12) LDP(13) LDP(14) LDP(15)
        GQ(0)  GQ(1)  GQ(2)  GQ(3)  GQ(4)  GQ(5)  GQ(6)  GQ(7)
        GQ(8)  GQ(9)  GQ(10) GQ(11) GQ(12) GQ(13) GQ(14) GQ(15)
        ACC(0)  ACC(1)  ACC(2)  ACC(3)  ACC(4)  ACC(5)  ACC(6)  ACC(7)
        ACC(8)  ACC(9)  ACC(10) ACC(11) ACC(12) ACC(13) ACC(14) ACC(15)
        e = eL;
    }
    // rare spill: block had >G_STAGE edges; finish from global
    for (; e < end; ++e) {
        Edge E0; { u32x2 q_ = ldnt((const u32x2*)(evg + e));
                   E0.c = (int)q_.x; E0.v = __uint_as_float(q_.y); }
        float fv0 = E0.v;
        GQ(0) ACC(0)
    }
#undef LDE
#undef LDP
#undef GQ
#undef ACC

    size_t o = ((size_t)row << 7) + ((size_t)h << 6) + (size_t)lane * 8;
    if (MODE == 1) {
        unsigned int m = mask2[(size_t)row * 16 + (h << 3) + lane];
        const float s = 1.0f / 0.9f;
        u16x8 gg;
        gg[0] = (m & 1u)   ? f2h(a0 * s) : (ushort)0;
        gg[1] = (m & 2u)   ? f2h(a1 * s) : (ushort)0;
        gg[2] = (m & 4u)   ? f2h(a2 * s) : (ushort)0;
        gg[3] = (m & 8u)   ? f2h(a3 * s) : (ushort)0;
        gg[4] = (m & 16u)  ? f2h(a4 * s) : (ushort)0;
        gg[5] = (m & 32u)  ? f2h(a5 * s) : (ushort)0;
        gg[6] = (m & 64u)  ? f2h(a6 * s) : (ushort)0;
        gg[7] = (m & 128u) ? f2h(a7 * s) : (ushort)0;
        stnt((u16x8*)(g2 + o), gg);
        u16x8 pp;
        pp[0] = f2h(a0); pp[1] = f2h(a1); pp[2] = f2h(a2); pp[3] = f2h(a3);
        pp[4] = f2h(a4); pp[5] = f2h(a5); pp[6] = f2h(a6); pp[7] = f2h(a7);
        stnt((u16x8*)(p16out + o), pp);
    } else {
        u32x4 eq = ldnt((const u32x4*)(emb16 + o));
        u32x4 pq = ldnt((const u32x4*)(p16in + o));
        float2 e0 = up2(eq.x), e1 = up2(eq.y), e2 = up2(eq.z), e3 = up2(eq.w);
        float2 p0 = up2(pq.x), p1 = up2(pq.y), p2 = up2(pq.z), p3 = up2(pq.w);
        const float t3 = 1.0f / 3.0f;
        f32x4 rA, rB;
        rA.x = (e0.x + p0.x + a0) * t3;
        rA.y = (e0.y + p0.y + a1) * t3;
        rA.z = (e1.x + p1.x + a2) * t3;
        rA.w = (e1.y + p1.y + a3) * t3;
        rB.x = (e2.x + p2.x + a4) * t3;
        rB.y = (e2.y + p2.y + a5) * t3;
        rB.z = (e3.x + p3.x + a6) * t3;
        rB.w = (e3.y + p3.y + a7) * t3;
        stnt((f32x4*)(out + o), rA);
        stnt((f32x4*)(out + o) + 1, rB);
    }
}

// ---- launch -------------------------------------------------------------

extern "C" void kernel_launch(void* const* d_in, const int* in_sizes, int n_in,
                              void* d_out, int out_size, void* d_ws, size_t ws_size,
                              hipStream_t stream) {
    const int* rows = (const int*)d_in[1];
    const int* cols = (const int*)d_in[2];
    const float* vals = (const float*)d_in[3];
    const float* emb = (const float*)d_in[4];
    const float* u1 = (const float*)d_in[5];
    const float* u2 = (const float*)d_in[6];
    float* out = (float*)d_out;

    const int N = in_sizes[0];
    const int E = in_sizes[1];
    const size_t ND = (size_t)N * DD;
    const int NW = (N + 1) / 2;          // packed counter words

    // workspace layout (~121 MB)
    char* ws = (char*)d_ws;
    Edge* ev     = (Edge*)ws;   ws += (size_t)E * sizeof(Edge);        // 12.8MB
    ushort* g1   = (ushort*)ws; ws += ND * sizeof(ushort);             // 25.6MB fp16
    ushort* g2   = (ushort*)ws; ws += ND * sizeof(ushort);             // 25.6MB fp16
    ushort* p16  = (ushort*)ws; ws += ND * sizeof(ushort);             // 25.6MB fp16 h1
    ushort* emb16= (ushort*)ws; ws += ND * sizeof(ushort);             // 25.6MB fp16 emb
    unsigned int* cnt16 = (unsigned int*)ws; ws += (size_t)NW * 4;     // 200KB packed
    int* rs      = (int*)ws;    ws += (size_t)N * sizeof(int);         // 0.4MB rowstart
    ushort* rank = (ushort*)ws; ws += (size_t)E * sizeof(ushort);      // 3.2MB
    int* bsum    = (int*)ws;    ws += 4096;
    unsigned char* mask2 = (unsigned char*)ws;                         // 1.6MB

    const int total8 = (int)(ND / 8);
    const int prepBlocks = (total8 + 255) / 256;
    const int gridE = (E + 255) / 256;
    const int gridFuse = prepBlocks > gridE ? prepBlocks : gridE;
    const int nScanBlocks = (N + SCAN_CHUNK - 1) / SCAN_CHUNK;
    const int gridRowX = (N + G_ROWS - 1) / G_ROWS;
    dim3 gridRow(gridRowX, 2, 1);

    hipMemsetAsync(cnt16, 0, (size_t)NW * 4, stream);
    // g1 stream + packed-16b hist (thread-level fusion)
    k_g1hist<<<gridFuse, 256, 0, stream>>>(emb, u1, g1, rows, cnt16, rank,
                                           total8, E);
    k_scan1<<<nScanBlocks, 256, 0, stream>>>(cnt16, rs, bsum, N);
    k_scan23<<<(N + 255) / 256, 256, 0, stream>>>(rs, bsum, nScanBlocks, N);
    // 1-edge/thread scatter + emb16/mask2 stream (thread-level fusion)
    k_scatter_prep<<<gridFuse, 256, 0, stream>>>(rows, cols, vals, rs, rank,
                                                 ev, emb, u2, emb16, mask2,
                                                 E, total8);
    // h1 = A*g1; p16 = fp16(h1); g2 = fp16(dropout(h1, mask2))
    k_gather<1><<<gridRow, 256, 0, stream>>>(rs, ev, g1, mask2, nullptr, nullptr,
                                             p16, g2, nullptr, N, E);
    // out = (emb16 + p16 + A*g2)/3
    k_gather<2><<<gridRow, 256, 0, stream>>>(rs, ev, g2, nullptr, emb16, p16,
                                             nullptr, nullptr, out, N, E);
}